// Round 5
// baseline (233.592 us; speedup 1.0000x reference)
//
#include <hip/hip_runtime.h>

#define B_ 512
#define T_ 1024
#define N_ 64
#define NA_ 66
#define CH 8
#define LN2 0.69314718055994530942f

typedef __attribute__((ext_vector_type(8))) short short8;
typedef __attribute__((ext_vector_type(4))) float f32x4;

__device__ __forceinline__ unsigned short bf16_rne(float f) {
    unsigned u = __float_as_uint(f);
    u += 0x7fffu + ((u >> 16) & 1u);
    return (unsigned short)(u >> 16);
}

__global__ __launch_bounds__(64) void crf_fwd(
    const int* __restrict__ y,      // [B,T]
    const float* __restrict__ P,    // [B,T,N]
    const int* __restrict__ lens,   // [B]
    const float* __restrict__ A,    // [NA,NA]
    float* __restrict__ out)        // [B]
{
    const int b = blockIdx.x;
    const int j = threadIdx.x;
    const int g = j >> 4;           // 16-lane group
    const int m = j & 15;
    const long pbase = (long)b * (T_ * N_);
    const int yb = b * T_;
    const int len = lens[b];        // in [T/2, T]

    // B-fragments of W = exp(Asub). Chosen k-maps (must match A-side packing):
    //   half1: k1(g,e) = 16*(e>>1) + 2g + (e&1)   (covers {k: k&8==0})
    //   half2: k2 = k1 + 8                         (covers {k: k&8==8})
    short8 B1[4], B2[4];
#pragma unroll
    for (int q = 0; q < 4; ++q) {
        const int col = 16 * q + m;
#pragma unroll
        for (int e = 0; e < 8; ++e) {
            const int k1 = 16 * (e >> 1) + 2 * g + (e & 1);
            B1[q][e] = (short)bf16_rne(__expf(A[k1 * NA_ + col]));
            B2[q][e] = (short)bf16_rne(__expf(A[(k1 + 8) * NA_ + col]));
        }
    }

    // bpermute byte-addresses (constant): a1 pulls lane 2g, a2 pulls lane 8+2g
    const int idx1 = (2 * g) << 2;
    const int idx2 = (8 + 2 * g) << 2;

    short8 a1, a2;                  // current A-fragments (z broadcast rows)
    float z0_, z1_, z2_, z3_;       // own cols m,16+m,32+m,48+m of current z

    // Build next A-frags from per-lane zq values, no LDS round-trip:
    // DPP neighbor swap -> cvt_pk (valid ordering on even lanes) -> 8 bpermutes.
    auto pack_bcast = [&](float q0, float q1, float q2, float q3) {
        const float s0 = __int_as_float(__builtin_amdgcn_update_dpp(
            0, __float_as_int(q0), 0xB1, 0xF, 0xF, true));
        const float s1 = __int_as_float(__builtin_amdgcn_update_dpp(
            0, __float_as_int(q1), 0xB1, 0xF, 0xF, true));
        const float s2 = __int_as_float(__builtin_amdgcn_update_dpp(
            0, __float_as_int(q2), 0xB1, 0xF, 0xF, true));
        const float s3 = __int_as_float(__builtin_amdgcn_update_dpp(
            0, __float_as_int(q3), 0xB1, 0xF, 0xF, true));
        int p0, p1, p2, p3;
        asm("v_cvt_pk_bf16_f32 %0, %1, %2" : "=v"(p0) : "v"(q0), "v"(s0));
        asm("v_cvt_pk_bf16_f32 %0, %1, %2" : "=v"(p1) : "v"(q1), "v"(s1));
        asm("v_cvt_pk_bf16_f32 %0, %1, %2" : "=v"(p2) : "v"(q2), "v"(s2));
        asm("v_cvt_pk_bf16_f32 %0, %1, %2" : "=v"(p3) : "v"(q3), "v"(s3));
        union { int i[4]; short8 s; } u1, u2;
        u1.i[0] = __builtin_amdgcn_ds_bpermute(idx1, p0);
        u1.i[1] = __builtin_amdgcn_ds_bpermute(idx1, p1);
        u1.i[2] = __builtin_amdgcn_ds_bpermute(idx1, p2);
        u1.i[3] = __builtin_amdgcn_ds_bpermute(idx1, p3);
        u2.i[0] = __builtin_amdgcn_ds_bpermute(idx2, p0);
        u2.i[1] = __builtin_amdgcn_ds_bpermute(idx2, p1);
        u2.i[2] = __builtin_amdgcn_ds_bpermute(idx2, p2);
        u2.i[3] = __builtin_amdgcn_ds_bpermute(idx2, p3);
        a1 = u1.s;
        a2 = u2.s;
    };

    // t=0 init: z0[c] = exp(A[START,c] + P[b,0,c]), c = 16q+m
    {
        const float i0 = __expf(A[N_ * NA_ + m]        + P[pbase + m]);
        const float i1 = __expf(A[N_ * NA_ + 16 + m]   + P[pbase + 16 + m]);
        const float i2 = __expf(A[N_ * NA_ + 32 + m]   + P[pbase + 32 + m]);
        const float i3 = __expf(A[N_ * NA_ + 48 + m]   + P[pbase + 48 + m]);
        z0_ = i0; z1_ = i1; z2_ = i2; z3_ = i3;
        pack_bcast(i0, i1, i2, i3);
    }
    int Mexp = 0;   // alpha_c = log(z_c) + Mexp*ln2

    auto step = [&](const float4 pr, bool renorm) {
        // off-chain: exp of the 4 P columns
        const float e0f = __expf(pr.x);
        const float e1f = __expf(pr.y);
        const float e2f = __expf(pr.z);
        const float e3f = __expf(pr.w);
        const f32x4 zero = {0.f, 0.f, 0.f, 0.f};
        // two parallel K-halves per column tile, combined with one add
        f32x4 u0 = __builtin_amdgcn_mfma_f32_16x16x32_bf16(a1, B1[0], zero, 0, 0, 0);
        f32x4 v0 = __builtin_amdgcn_mfma_f32_16x16x32_bf16(a2, B2[0], zero, 0, 0, 0);
        f32x4 u1 = __builtin_amdgcn_mfma_f32_16x16x32_bf16(a1, B1[1], zero, 0, 0, 0);
        f32x4 v1 = __builtin_amdgcn_mfma_f32_16x16x32_bf16(a2, B2[1], zero, 0, 0, 0);
        f32x4 u2 = __builtin_amdgcn_mfma_f32_16x16x32_bf16(a1, B1[2], zero, 0, 0, 0);
        f32x4 v2 = __builtin_amdgcn_mfma_f32_16x16x32_bf16(a2, B2[2], zero, 0, 0, 0);
        f32x4 u3 = __builtin_amdgcn_mfma_f32_16x16x32_bf16(a1, B1[3], zero, 0, 0, 0);
        f32x4 v3 = __builtin_amdgcn_mfma_f32_16x16x32_bf16(a2, B2[3], zero, 0, 0, 0);
        const float c0 = u0[0] + v0[0];
        const float c1 = u1[0] + v1[0];
        const float c2 = u2[0] + v2[0];
        const float c3 = u3[0] + v3[0];
        float s0, s1, s2, s3;
        if (renorm) {   // direct (zero-delay) exponent renorm, stable
            const int sb = __builtin_amdgcn_readfirstlane(__float_as_int(c0));
            const int e0 = ((sb >> 23) & 0xff) - 127;
            s0 = ldexpf(e0f, -e0); s1 = ldexpf(e1f, -e0);
            s2 = ldexpf(e2f, -e0); s3 = ldexpf(e3f, -e0);
            Mexp += e0;
        } else {        // deterministic 2^-6, exact
            s0 = e0f * 0.015625f; s1 = e1f * 0.015625f;
            s2 = e2f * 0.015625f; s3 = e3f * 0.015625f;
            Mexp += 6;
        }
        z0_ = c0 * s0; z1_ = c1 * s1; z2_ = c2 * s2; z3_ = c3 * s3;
        pack_bcast(z0_, z1_, z2_, z3_);
    };

    const int nsteps = len - 1;            // >= 511
    const int nchunks = nsteps / CH;

    float4 prA[CH], prB[CH];
    auto issue = [&](int k, float4 (&dst)[CH]) {
#pragma unroll
        for (int u = 0; u < CH; ++u) {
            int t = 1 + k * CH + u;
            t = t < T_ ? t : T_ - 1;       // clamp; beyond-len values unused
            const float* row = P + pbase + (long)t * N_;
            dst[u] = make_float4(row[m], row[16 + m], row[32 + m], row[48 + m]);
        }
    };
    auto runCH = [&](float4 (&src)[CH]) {
#pragma unroll
        for (int u = 0; u < CH; ++u)
            step(src[u], u == 0);
    };
    auto runTail = [&](float4 (&src)[CH], int tcnt) {
#pragma unroll
        for (int u = 0; u < CH; ++u)
            if (u < tcnt)                  // wave-uniform
                step(src[u], u == 0);
    };

    issue(0, prA);
    int c = 0;
    for (; c + 1 < nchunks; c += 2) {
        issue(c + 1, prB); runCH(prA);
        issue(c + 2, prA); runCH(prB);
    }
    if (c < nchunks) {
        issue(c + 1, prB); runCH(prA);
        runTail(prB, nsteps - nchunks * CH);
    } else {
        runTail(prA, nsteps - nchunks * CH);
    }

    // ---- logZ = Mexp*ln2 + log( sum_c z_c * exp(A[c, END]) ) ----
    float send = z0_ * __expf(A[m * NA_ + (N_ + 1)])
               + z1_ * __expf(A[(16 + m) * NA_ + (N_ + 1)])
               + z2_ * __expf(A[(32 + m) * NA_ + (N_ + 1)])
               + z3_ * __expf(A[(48 + m) * NA_ + (N_ + 1)]);
#pragma unroll
    for (int off = 8; off >= 1; off >>= 1)   // reduce over m within 16-lane group
        send += __shfl_xor(send, off, 64);
    const float logZ = (float)Mexp * LN2 + __logf(send);

    // ---- score (epilogue, batched gathers over all 64 lanes) ----
    const int NK = T_ / 64;                // 16
    int yk[NK];
#pragma unroll
    for (int k = 0; k < NK; ++k)
        yk[k] = y[yb + j + 64 * k];
    float em = 0.f, inn = 0.f;
    int carry = 0;
#pragma unroll
    for (int k = 0; k < NK; ++k) {
        const int t = j + 64 * k;
        const bool v = t < len;
        em += v ? P[pbase + t * N_ + yk[k]] : 0.f;
        int yp = __shfl_up(yk[k], 1, 64);
        if (j == 0) yp = carry;
        carry = __shfl(yk[k], 63, 64);
        inn += (v && t >= 1) ? A[yp * NA_ + yk[k]] : 0.f;
    }
#pragma unroll
    for (int off = 32; off >= 1; off >>= 1) {
        em  += __shfl_xor(em, off, 64);
        inn += __shfl_xor(inn, off, 64);
    }
    if (j == 0) {
        const int y0 = y[yb];
        const float start = A[N_ * NA_ + y0];
        const int ylast = y[yb + len - 1];
        const float endv = A[ylast * NA_ + (N_ + 1)];
        out[b] = logZ - (em + start + inn + endv);
    }
}

extern "C" void kernel_launch(void* const* d_in, const int* in_sizes, int n_in,
                              void* d_out, int out_size, void* d_ws, size_t ws_size,
                              hipStream_t stream) {
    const int* y = (const int*)d_in[0];
    const float* P = (const float*)d_in[1];
    const int* lens = (const int*)d_in[2];
    const float* A = (const float*)d_in[3];
    float* out = (float*)d_out;
    crf_fwd<<<dim3(B_), dim3(64), 0, stream>>>(y, P, lens, A, out);
}

// Round 6
// 107.670 us; speedup vs baseline: 2.1695x; 2.1695x over previous
//
#include <hip/hip_runtime.h>

#define B_ 512
#define T_ 1024
#define N_ 64
#define NA_ 66
#define CH 8
#define LN2 0.69314718055994530942f

typedef __attribute__((ext_vector_type(8))) short short8;
typedef __attribute__((ext_vector_type(4))) float f32x4;

#define MFMA(a, bfr) __builtin_amdgcn_mfma_f32_16x16x32_bf16((a), (bfr), zeroc, 0, 0, 0)

__device__ __forceinline__ unsigned short bf16_rne(float f) {
    unsigned u = __float_as_uint(f);
    u += 0x7fffu + ((u >> 16) & 1u);
    return (unsigned short)(u >> 16);
}

__global__ __launch_bounds__(128) void crf_fb(
    const int* __restrict__ y,      // [B,T]
    const float* __restrict__ P,    // [B,T,N]
    const int* __restrict__ lens,   // [B]
    const float* __restrict__ A,    // [NA,NA]
    float* __restrict__ out)        // [B]
{
    const int b = blockIdx.x;
    const int tid = threadIdx.x;
    const int wv = tid >> 6;        // wave 0: forward alpha; wave 1: backward beta
    const int j = tid & 63;         // lane == state/column index
    const int g = j >> 4;
    const int m = j & 15;
    const long pbase = (long)b * (T_ * N_);
    const int yb = b * T_;
    const int len = lens[b];        // in [T/2, T]
    const int tsplit = (len - 1) >> 1;
    const int nsteps = wv ? (len - 1 - tsplit) : tsplit;   // each <= 512

    // B-fragments (round-4 proven k-map): wave0 holds W=exp(Asub), wave1 W^T.
    short8 Bf[4][2];
#pragma unroll
    for (int cb = 0; cb < 4; ++cb) {
        const int col = 16 * cb + m;
#pragma unroll
        for (int kh = 0; kh < 2; ++kh) {
#pragma unroll
            for (int e = 0; e < 8; ++e) {
                const int r = 32 * kh + 8 * g + e;
                const float av = wv ? A[col * NA_ + r] : A[r * NA_ + col];
                Bf[cb][kh][e] = (short)bf16_rne(__expf(av));
            }
        }
    }

    __shared__ __align__(16) unsigned short zl[2][N_];
    __shared__ float zfin[2][N_];
    __shared__ float part[2];
    __shared__ int msh[2];
    unsigned short* zw = zl[wv];

    // init: fwd z = exp(A[START,j] + P[0,j]); bwd w = exp(A[j,END])
    float zown = wv ? __expf(A[j * NA_ + (N_ + 1)])
                    : __expf(A[N_ * NA_ + j] + P[pbase + j]);
    int Mexp = 0;
    short8 a1, a2;

    // fwd step: z' = (z*W) .* ep[t] * 2^-6;  bwd: w' = ((ep[t+1].*w)*W^T) * 2^-6
    auto step = [&](float praw, bool renorm) {
        const float ep = __expf(praw);
        float vw;
        if (wv) vw = renorm ? zown * ep : zown * (ep * 0.015625f);
        else    vw = zown;
        zw[j] = bf16_rne(vw);
        __builtin_memcpy(&a1, (const void*)(zw + 8 * g), 16);
        __builtin_memcpy(&a2, (const void*)(zw + 32 + 8 * g), 16);
        const f32x4 zeroc = {0.f, 0.f, 0.f, 0.f};
        f32x4 u0 = MFMA(a1, Bf[0][0]), v0 = MFMA(a2, Bf[0][1]);
        f32x4 u1 = MFMA(a1, Bf[1][0]), v1 = MFMA(a2, Bf[1][1]);
        f32x4 u2 = MFMA(a1, Bf[2][0]), v2 = MFMA(a2, Bf[2][1]);
        f32x4 u3 = MFMA(a1, Bf[3][0]), v3 = MFMA(a2, Bf[3][1]);
        const float su01 = (g & 1) ? u1[0] : u0[0];
        const float su23 = (g & 1) ? u3[0] : u2[0];
        const float su   = (g & 2) ? su23 : su01;
        const float sv01 = (g & 1) ? v1[0] : v0[0];
        const float sv23 = (g & 1) ? v3[0] : v2[0];
        const float sv   = (g & 2) ? sv23 : sv01;
        const float sel = su + sv;       // own column j of S
        if (renorm) {                    // direct (zero-delay) renorm, stable
            const int sb = __builtin_amdgcn_readfirstlane(__float_as_int(sel));
            const int e0 = ((sb >> 23) & 0xff) - 127;
            zown = wv ? ldexpf(sel, -e0) : ldexpf(sel, -e0) * ep;
            Mexp += e0;
        } else {                         // exact 2^-6 per step
            zown = wv ? sel : sel * (ep * 0.015625f);
            Mexp += 6;
        }
    };

    const int nchunks = nsteps / CH;
    float prA[CH], prB[CH];
    auto issue = [&](int k, float (&dst)[CH]) {
#pragma unroll
        for (int u = 0; u < CH; ++u) {
            const int i = k * CH + u;
            int t = wv ? (len - 1 - i) : (1 + i);
            t = t < 0 ? 0 : (t >= T_ ? T_ - 1 : t);   // clamp; overshoot unused
            dst[u] = P[pbase + (long)t * N_ + j];
        }
    };
    auto runCH = [&](float (&src)[CH]) {
#pragma unroll
        for (int u = 0; u < CH; ++u) step(src[u], u == 0);
    };
    auto runTail = [&](float (&src)[CH], int tcnt) {
#pragma unroll
        for (int u = 0; u < CH; ++u)
            if (u < tcnt) step(src[u], u == 0);       // wave-uniform
    };

    issue(0, prA);
    int c = 0;
    for (; c + 1 < nchunks; c += 2) {
        issue(c + 1, prB); runCH(prA);
        issue(c + 2, prA); runCH(prB);
    }
    if (c < nchunks) {
        issue(c + 1, prB); runCH(prA);
        runTail(prB, nsteps - nchunks * CH);
    } else {
        runTail(prA, nsteps - nchunks * CH);
    }

    zfin[wv][j] = zown;
    if (j == 0) msh[wv] = Mexp;

    // ---- score partials: wave0 emit, wave1 inner ----
    const int NK = T_ / 64;             // 16
    int yk[NK];
#pragma unroll
    for (int k = 0; k < NK; ++k)
        yk[k] = y[yb + j + 64 * k];
    float sc = 0.f;
    if (wv == 0) {
#pragma unroll
        for (int k = 0; k < NK; ++k) {
            const int t = j + 64 * k;
            sc += (t < len) ? P[pbase + (long)t * N_ + yk[k]] : 0.f;
        }
    } else {
        int carry = 0;
#pragma unroll
        for (int k = 0; k < NK; ++k) {
            const int t = j + 64 * k;
            int yp = __shfl_up(yk[k], 1, 64);
            if (j == 0) yp = carry;
            carry = __shfl(yk[k], 63, 64);
            sc += (t >= 1 && t < len) ? A[yp * NA_ + yk[k]] : 0.f;
        }
    }
#pragma unroll
    for (int off = 32; off >= 1; off >>= 1)
        sc += __shfl_xor(sc, off, 64);
    if (j == 0) part[wv] = sc;
    __syncthreads();

    // ---- combine: logZ = log(sum_j zF_j*zB_j) + (MexpF+MexpB)*ln2 ----
    if (wv == 0) {
        float send = zfin[0][j] * zfin[1][j];
#pragma unroll
        for (int off = 32; off >= 1; off >>= 1)
            send += __shfl_xor(send, off, 64);
        if (j == 0) {
            const float logZ = __logf(send) + (float)(msh[0] + msh[1]) * LN2;
            const int y0 = y[yb];
            const float start = A[N_ * NA_ + y0];
            const int ylast = y[yb + len - 1];
            const float endv = A[ylast * NA_ + (N_ + 1)];
            out[b] = logZ - (part[0] + part[1] + start + endv);
        }
    }
}

extern "C" void kernel_launch(void* const* d_in, const int* in_sizes, int n_in,
                              void* d_out, int out_size, void* d_ws, size_t ws_size,
                              hipStream_t stream) {
    const int* y = (const int*)d_in[0];
    const float* P = (const float*)d_in[1];
    const int* lens = (const int*)d_in[2];
    const float* A = (const float*)d_in[3];
    float* out = (float*)d_out;
    crf_fb<<<dim3(B_), dim3(128), 0, stream>>>(y, P, lens, A, out);
}

// Round 7
// 99.369 us; speedup vs baseline: 2.3508x; 1.0835x over previous
//
#include <hip/hip_runtime.h>

#define B_ 512
#define T_ 1024
#define N_ 64
#define NA_ 66
#define CH 8
#define LN2 0.69314718055994530942f

typedef __attribute__((ext_vector_type(8))) short short8;
typedef __attribute__((ext_vector_type(4))) float f32x4;

__device__ __forceinline__ unsigned short bf16_rne(float f) {
    unsigned u = __float_as_uint(f);
    u += 0x7fffu + ((u >> 16) & 1u);
    return (unsigned short)(u >> 16);
}

__global__ __launch_bounds__(128) void crf_fb(
    const int* __restrict__ y,      // [B,T]
    const float* __restrict__ P,    // [B,T,N]
    const int* __restrict__ lens,   // [B]
    const float* __restrict__ A,    // [NA,NA]
    float* __restrict__ out)        // [B]
{
    const int b = blockIdx.x;
    const int tid = threadIdx.x;
    const int wv = tid >> 6;        // wave 0: forward alpha; wave 1: backward beta
    const int j = tid & 63;         // lane == state/column index
    const int g = j >> 4;
    const int m = j & 15;
    const long pbase = (long)b * (T_ * N_);
    const int yb = b * T_;
    const int len = lens[b];        // in [T/2, T]
    const int tsplit = (len - 1) >> 1;
    const int nsteps = wv ? (len - 1 - tsplit) : tsplit;   // each <= 512

    // B-fragments (round-4 proven k-map): wave0 holds W=exp(Asub), wave1 W^T.
    short8 Bf[4][2];
#pragma unroll
    for (int cb = 0; cb < 4; ++cb) {
        const int col = 16 * cb + m;
#pragma unroll
        for (int kh = 0; kh < 2; ++kh) {
#pragma unroll
            for (int e = 0; e < 8; ++e) {
                const int r = 32 * kh + 8 * g + e;
                const float av = wv ? A[col * NA_ + r] : A[r * NA_ + col];
                Bf[cb][kh][e] = (short)bf16_rne(__expf(av));
            }
        }
    }

    __shared__ __align__(16) unsigned short zl[2][N_];
    __shared__ float zfin[2][N_];
    __shared__ float part[2];
    __shared__ int msh[2];
    unsigned short* zw = zl[wv];
    const float isB = wv ? 1.0f : 0.0f;

    // init: fwd z = exp(A[START,j] + P[0,j]); bwd w = exp(A[j,END])
    float zown = wv ? __expf(A[j * NA_ + (N_ + 1)])
                    : __expf(A[N_ * NA_ + j] + P[pbase + j]);
    int Mexp = 0;
    short8 a1, a2;

    // One step, r4-verbatim structure. fwd: z' = sel(z*W) * s;  bwd: w' = sel((w*s)*W^T)
    auto step = [&](float praw, bool renorm) {
        const float ep = __expf(praw);                    // off-chain
        const float eps = ep * 0.015625f;                 // exact 2^-6
        const float sc = renorm ? ep : eps;
        const float wmul = isB * sc + (1.0f - isB);       // bwd: sc, fwd: 1
        const float pmul = isB + (1.0f - isB) * sc;       // bwd: 1,  fwd: sc
        zw[j] = bf16_rne(zown * wmul);
        __builtin_memcpy(&a1, (const void*)(zw + 8 * g), 16);
        __builtin_memcpy(&a2, (const void*)(zw + 32 + 8 * g), 16);
        f32x4 c0 = {0.f, 0.f, 0.f, 0.f};
        f32x4 c1 = {0.f, 0.f, 0.f, 0.f};
        f32x4 c2 = {0.f, 0.f, 0.f, 0.f};
        f32x4 c3 = {0.f, 0.f, 0.f, 0.f};
        c0 = __builtin_amdgcn_mfma_f32_16x16x32_bf16(a1, Bf[0][0], c0, 0, 0, 0);
        c0 = __builtin_amdgcn_mfma_f32_16x16x32_bf16(a2, Bf[0][1], c0, 0, 0, 0);
        c1 = __builtin_amdgcn_mfma_f32_16x16x32_bf16(a1, Bf[1][0], c1, 0, 0, 0);
        c1 = __builtin_amdgcn_mfma_f32_16x16x32_bf16(a2, Bf[1][1], c1, 0, 0, 0);
        c2 = __builtin_amdgcn_mfma_f32_16x16x32_bf16(a1, Bf[2][0], c2, 0, 0, 0);
        c2 = __builtin_amdgcn_mfma_f32_16x16x32_bf16(a2, Bf[2][1], c2, 0, 0, 0);
        c3 = __builtin_amdgcn_mfma_f32_16x16x32_bf16(a1, Bf[3][0], c3, 0, 0, 0);
        c3 = __builtin_amdgcn_mfma_f32_16x16x32_bf16(a2, Bf[3][1], c3, 0, 0, 0);
        const float c01 = (g & 1) ? c1[0] : c0[0];
        const float c23 = (g & 1) ? c3[0] : c2[0];
        float sel = (g & 2) ? c23 : c01;                  // own column j of S
        if (renorm) {                                     // direct renorm, stable
            const int sb = __builtin_amdgcn_readfirstlane(__float_as_int(c0[0]));
            const int e0 = ((sb >> 23) & 0xff) - 127;
            sel = ldexpf(sel, -e0);
            Mexp += e0;
        } else {
            Mexp += 6;
        }
        zown = sel * pmul;
    };

    const int nchunks = nsteps / CH;
    float prA[CH], prB[CH];
    auto issue = [&](int k, float (&dst)[CH]) {
#pragma unroll
        for (int u = 0; u < CH; ++u) {
            const int i = k * CH + u;
            int t = wv ? (len - 1 - i) : (1 + i);
            t = t < 0 ? 0 : (t >= T_ ? T_ - 1 : t);       // clamp; overshoot unused
            dst[u] = P[pbase + (long)t * N_ + j];
        }
    };
    auto runCH = [&](float (&src)[CH]) {
#pragma unroll
        for (int u = 0; u < CH; ++u) step(src[u], u == 0);
    };
    auto runTail = [&](float (&src)[CH], int tcnt) {
#pragma unroll
        for (int u = 0; u < CH; ++u)
            if (u < tcnt) step(src[u], u == 0);           // wave-uniform
    };

    issue(0, prA);
    int c = 0;
    for (; c + 1 < nchunks; c += 2) {
        issue(c + 1, prB); runCH(prA);
        issue(c + 2, prA); runCH(prB);
    }
    if (c < nchunks) {
        issue(c + 1, prB); runCH(prA);
        runTail(prB, nsteps - nchunks * CH);
    } else {
        runTail(prA, nsteps - nchunks * CH);
    }

    zfin[wv][j] = zown;
    if (j == 0) msh[wv] = Mexp;

    // ---- score partials: wave0 emit, wave1 inner ----
    const int NK = T_ / 64;             // 16
    int yk[NK];
#pragma unroll
    for (int k = 0; k < NK; ++k)
        yk[k] = y[yb + j + 64 * k];
    float sc = 0.f;
    if (wv == 0) {
#pragma unroll
        for (int k = 0; k < NK; ++k) {
            const int t = j + 64 * k;
            sc += (t < len) ? P[pbase + (long)t * N_ + yk[k]] : 0.f;
        }
    } else {
        int carry = 0;
#pragma unroll
        for (int k = 0; k < NK; ++k) {
            const int t = j + 64 * k;
            int yp = __shfl_up(yk[k], 1, 64);
            if (j == 0) yp = carry;
            carry = __shfl(yk[k], 63, 64);
            sc += (t >= 1 && t < len) ? A[yp * NA_ + yk[k]] : 0.f;
        }
    }
#pragma unroll
    for (int off = 32; off >= 1; off >>= 1)
        sc += __shfl_xor(sc, off, 64);
    if (j == 0) part[wv] = sc;
    __syncthreads();

    // ---- combine: logZ = log(sum_j zF_j*zB_j) + (MexpF+MexpB)*ln2 ----
    if (wv == 0) {
        float send = zfin[0][j] * zfin[1][j];
#pragma unroll
        for (int off = 32; off >= 1; off >>= 1)
            send += __shfl_xor(send, off, 64);
        if (j == 0) {
            const float logZ = __logf(send) + (float)(msh[0] + msh[1]) * LN2;
            const int y0 = y[yb];
            const float start = A[N_ * NA_ + y0];
            const int ylast = y[yb + len - 1];
            const float endv = A[ylast * NA_ + (N_ + 1)];
            out[b] = logZ - (part[0] + part[1] + start + endv);
        }
    }
}

extern "C" void kernel_launch(void* const* d_in, const int* in_sizes, int n_in,
                              void* d_out, int out_size, void* d_ws, size_t ws_size,
                              hipStream_t stream) {
    const int* y = (const int*)d_in[0];
    const float* P = (const float*)d_in[1];
    const int* lens = (const int*)d_in[2];
    const float* A = (const float*)d_in[3];
    float* out = (float*)d_out;
    crf_fb<<<dim3(B_), dim3(128), 0, stream>>>(y, P, lens, A, out);
}